// Round 5
// baseline (281.044 us; speedup 1.0000x reference)
//
#include <hip/hip_runtime.h>
#include <math.h>

// Problem constants (fixed by reference setup_inputs)
#define T_TOK 16384
#define DDIM  2048
#define NE    64
#define NPLANE (NE * DDIM)      // 131072 elements per W split plane
#define NBLK  512               // main-kernel grid (32 tokens each)

typedef __attribute__((ext_vector_type(8))) short short8;   // 8 bf16 MFMA frag
typedef __attribute__((ext_vector_type(4))) float floatx4;  // MFMA C/D

union Frag8 { unsigned short u[8]; short8 v; };

__device__ __forceinline__ unsigned int bf16_rne_bits(float x) {
    unsigned int u = __builtin_bit_cast(unsigned int, x);
    return (u + 0x7fffu + ((u >> 16) & 1u)) & 0xffff0000u;
}

// ---- pre-kernel: exact 3-way bf16 split of W, PACKED in MFMA-frag order ----
// packed idx = ((kc*4 + et)*4 + q)*128 + cl*8 + j
//   expert e = et*16 + cl,  k = kc*32 + q*8 + j
// => a wave's B-frag load (fixed p, kc, et; lanes (q,cl)) is 1 KB contiguous.
__global__ void wsplit_kernel(const float* __restrict__ W,
                              unsigned short* __restrict__ wh,
                              unsigned short* __restrict__ wm,
                              unsigned short* __restrict__ wl) {
    int i  = blockIdx.x * 256 + threadIdx.x;   // grid covers exactly NPLANE
    int j  = i & 7;
    int cl = (i >> 3) & 15;
    int q  = (i >> 7) & 3;
    int et = (i >> 9) & 3;
    int kc = i >> 11;                          // 0..63
    int e  = et * 16 + cl;
    int k  = kc * 32 + q * 8 + j;
    float w = W[e * DDIM + k];
    unsigned int hb = bf16_rne_bits(w);
    float r  = w - __builtin_bit_cast(float, hb);   // exact
    unsigned int mb = bf16_rne_bits(r);
    float r2 = r - __builtin_bit_cast(float, mb);   // exact
    unsigned int lb = bf16_rne_bits(r2);            // |err| <= 2^-24 |w|
    wh[i] = (unsigned short)(hb >> 16);
    wm[i] = (unsigned short)(mb >> 16);
    wl[i] = (unsigned short)(lb >> 16);
}

// ---- main: R4 structure with REGISTER staging instead of global_load_lds.
// 1024 thr = 16 waves = nh(2) x kq(8), 2 blk/CU.
// Phase c: barrier -> issue global float4 loads for window c+1 (lane-linear,
// fully coalesced) -> compute phase c (packed-B frag loads, LDS A reads +
// 3-way split, 24 MFMA) -> ds_write_b128 window c+1 into alt buffer (XOR
// swizzle applied on the LDS-write address; LDS image bit-identical to R4).
// T14 async-split: the full phase of compute hides the HBM latency, and the
// plain vector loads coalesce at line granularity (vs 16B DMA granules).
// LDS: As[2][8192] f32 (64 KB, lg overlays after loop) + ured 4 KB.
__global__ __launch_bounds__(1024, 8)
void router_main(const float* __restrict__ x,
                 const unsigned short* __restrict__ wh,
                 const unsigned short* __restrict__ wm,
                 const unsigned short* __restrict__ wl,
                 float* __restrict__ out, float* __restrict__ usage_part) {
    __shared__ float As[2 * 8192];     // 64 KB staging; lg overlays after loop
    __shared__ float ured[16][NE];     // 4 KB
    float* lg = As;                    // [8][32][64] overlay (written post-loop)

    const int tid  = threadIdx.x;
    const int lane = tid & 63;
    const int wv   = __builtin_amdgcn_readfirstlane(tid >> 6);  // 0..15
    const int nh   = wv & 1;     // expert half (32 experts)
    const int kq   = wv >> 1;    // k sub-slice within each 256-k window
    const int cl   = lane & 15;  // frag row index (token / expert)
    const int q    = lane >> 4;  // frag k-quad
    const int t0   = blockIdx.x * 32;

    // A staging role: wave stages local tokens 2wv, 2wv+1.
    // Global source lane-linear (lane l -> 16B chunk l of the 1 KB window);
    // XOR swizzle (chunk ^ (tl&7)) applied on the ds_write address, so the
    // LDS image is bit-identical to R4's DMA layout.
    const int tlA0 = 2 * wv, tlA1 = 2 * wv + 1;
    const float* ax0 = x + (size_t)(t0 + tlA0) * DDIM + (lane << 2);
    const float* ax1 = x + (size_t)(t0 + tlA1) * DDIM + (lane << 2);
    const int wofs0 = tlA0 * 256 + ((lane ^ (tlA0 & 7)) << 2);
    const int wofs1 = tlA1 * 256 + ((lane ^ (tlA1 & 7)) << 2);

    floatx4 acc[2][2];
#pragma unroll
    for (int mt = 0; mt < 2; ++mt)
#pragma unroll
        for (int nt = 0; nt < 2; ++nt)
            acc[mt][nt] = (floatx4){0.f, 0.f, 0.f, 0.f};

    // B frag element offsets (phase c adds c*16384):
    //   ((c*8 + kq)*4 + (nh*2+nt))*512 + (q*16+cl)*8
    const unsigned lofs   = (unsigned)((q * 16 + cl) << 3);
    const unsigned bfrag0 = ((unsigned)(kq * 4 + nh * 2 + 0) << 9) + lofs;
    const unsigned bfrag1 = ((unsigned)(kq * 4 + nh * 2 + 1) << 9) + lofs;

    // prologue: stage window 0 -> buffer 0 (load -> reg -> LDS)
    {
        float4 p0 = *(const float4*)(ax0);
        float4 p1 = *(const float4*)(ax1);
        *(float4*)(As + wofs0) = p0;
        *(float4*)(As + wofs1) = p1;
    }

#pragma unroll 1
    for (int c = 0; c < 8; ++c) {
        __syncthreads();   // publishes window c; frees buf[(c+1)&1]

        // issue next-window global loads FIRST (HBM latency hides under the
        // whole phase body); consumed by the ds_write at phase end
        float4 n0, n1;
        if (c + 1 < 8) {
            n0 = *(const float4*)(ax0 + (c + 1) * 256);
            n1 = *(const float4*)(ax1 + (c + 1) * 256);
        }

        // B frags: two 1-KB contiguous loads x 3 planes
        const unsigned bo = (unsigned)c * 16384u;
        uint4 cb[2][3];
        {
            const unsigned o0 = bo + bfrag0, o1 = bo + bfrag1;
            cb[0][0] = *(const uint4*)(wh + o0);
            cb[0][1] = *(const uint4*)(wm + o0);
            cb[0][2] = *(const uint4*)(wl + o0);
            cb[1][0] = *(const uint4*)(wh + o1);
            cb[1][1] = *(const uint4*)(wm + o1);
            cb[1][2] = *(const uint4*)(wl + o1);
        }

        // A frags from LDS (chunk-XOR by cl&7) + truncation 3-way split
        const float* buf = As + (c & 1) * 8192;
        const int h0 = (kq * 8 + q * 2) ^ (cl & 7);   // swizzled 16-B chunk idx
        short8 Ah[2], Am[2], Al[2];
#pragma unroll
        for (int mt = 0; mt < 2; ++mt) {
            const float* ap = buf + (mt * 16 + cl) * 256;
            float4 a0 = *(const float4*)(ap + h0 * 4);         // k j=0..3
            float4 a1 = *(const float4*)(ap + (h0 ^ 1) * 4);   // k j=4..7
            float f[8] = {a0.x, a0.y, a0.z, a0.w, a1.x, a1.y, a1.z, a1.w};
            Frag8 fh, fm, fl;
#pragma unroll
            for (int j = 0; j < 8; ++j) {
                unsigned int ub = __builtin_bit_cast(unsigned int, f[j]);
                unsigned int hb = ub & 0xffff0000u;
                float r = f[j] - __builtin_bit_cast(float, hb);   // exact
                unsigned int rb = __builtin_bit_cast(unsigned int, r);
                unsigned int mb = rb & 0xffff0000u;
                float r2 = r - __builtin_bit_cast(float, mb);     // exact
                unsigned int lb = __builtin_bit_cast(unsigned int, r2);
                fh.u[j] = (unsigned short)(hb >> 16);
                fm.u[j] = (unsigned short)(mb >> 16);
                fl.u[j] = (unsigned short)(lb >> 16);
            }
            Ah[mt] = fh.v; Am[mt] = fm.v; Al[mt] = fl.v;
        }

        // 6 passes: hh + hm + mh + mm + hl + lh
#pragma unroll
        for (int mt = 0; mt < 2; ++mt)
#pragma unroll
            for (int nt = 0; nt < 2; ++nt) {
                short8 Bh = __builtin_bit_cast(short8, cb[nt][0]);
                short8 Bm = __builtin_bit_cast(short8, cb[nt][1]);
                short8 Bl = __builtin_bit_cast(short8, cb[nt][2]);
                floatx4 a = acc[mt][nt];
                a = __builtin_amdgcn_mfma_f32_16x16x32_bf16(Ah[mt], Bh, a, 0, 0, 0);
                a = __builtin_amdgcn_mfma_f32_16x16x32_bf16(Ah[mt], Bm, a, 0, 0, 0);
                a = __builtin_amdgcn_mfma_f32_16x16x32_bf16(Am[mt], Bh, a, 0, 0, 0);
                a = __builtin_amdgcn_mfma_f32_16x16x32_bf16(Am[mt], Bm, a, 0, 0, 0);
                a = __builtin_amdgcn_mfma_f32_16x16x32_bf16(Ah[mt], Bl, a, 0, 0, 0);
                a = __builtin_amdgcn_mfma_f32_16x16x32_bf16(Al[mt], Bh, a, 0, 0, 0);
                acc[mt][nt] = a;
            }

        // write next window into the alternate buffer (reg -> LDS); the
        // implicit vmcnt wait lands AFTER a full phase of compute
        if (c + 1 < 8) {
            float* nb = As + ((c + 1) & 1) * 8192;
            *(float4*)(nb + wofs0) = n0;
            *(float4*)(nb + wofs1) = n1;
        }
    }

    __syncthreads();   // all waves done reading As -> safe to overlay lg

    // partial logits -> lg. D layout: n(expert) = lane&15, m(token) = q*4+reg
#pragma unroll
    for (int mt = 0; mt < 2; ++mt)
#pragma unroll
        for (int nt = 0; nt < 2; ++nt)
#pragma unroll
            for (int r = 0; r < 4; ++r)
                lg[kq * 2048 + (mt * 16 + q * 4 + r) * 64 + nh * 32 + nt * 16 + cl]
                    = acc[mt][nt][r];
    __syncthreads();

    // ---- epilogue (verified rounds 0-4): lane = expert, 2 tokens/wave ----
    float usage_acc = 0.f;
#pragma unroll 1
    for (int j = 0; j < 2; ++j) {
        const int tl = wv * 2 + j;
        const int t  = t0 + tl;
        float l = (((lg[0 * 2048 + tl * 64 + lane] + lg[1 * 2048 + tl * 64 + lane]) +
                    (lg[2 * 2048 + tl * 64 + lane] + lg[3 * 2048 + tl * 64 + lane])) +
                   ((lg[4 * 2048 + tl * 64 + lane] + lg[5 * 2048 + tl * 64 + lane]) +
                    (lg[6 * 2048 + tl * 64 + lane] + lg[7 * 2048 + tl * 64 + lane])));

        float v1 = l; int i1 = lane;
#pragma unroll
        for (int off = 32; off >= 1; off >>= 1) {
            float ov = __shfl_xor(v1, off, 64);
            int   oi = __shfl_xor(i1, off, 64);
            if (ov > v1 || (ov == v1 && oi < i1)) { v1 = ov; i1 = oi; }
        }
        float lm = (lane == i1) ? -INFINITY : l;
        float v2 = lm; int i2 = lane;
#pragma unroll
        for (int off = 32; off >= 1; off >>= 1) {
            float ov = __shfl_xor(v2, off, 64);
            int   oi = __shfl_xor(i2, off, 64);
            if (ov > v2 || (ov == v2 && oi < i2)) { v2 = ov; i2 = oi; }
        }

        float p = expf(l - v1);
        float s = p;
#pragma unroll
        for (int off = 32; off >= 1; off >>= 1) s += __shfl_xor(s, off, 64);

        float e2  = expf(v2 - v1);
        float rcp = 1.0f / (1.0f + e2);
        usage_acc += p / s;

        if (lane == 0) {
            out[(size_t)t * 2 + 0]         = (float)i1;
            out[(size_t)t * 2 + 1]         = (float)i2;
            out[32768 + (size_t)t * 2 + 0] = rcp;
            out[32768 + (size_t)t * 2 + 1] = e2 * rcp;
        }
    }

    // per-block usage partials (no atomics; deterministic)
    ured[wv][lane] = usage_acc;
    __syncthreads();
    if (wv == 0) {
        float s = (((ured[0][lane] + ured[1][lane]) + (ured[2][lane] + ured[3][lane])) +
                   ((ured[4][lane] + ured[5][lane]) + (ured[6][lane] + ured[7][lane]))) +
                  (((ured[8][lane] + ured[9][lane]) + (ured[10][lane] + ured[11][lane])) +
                   ((ured[12][lane] + ured[13][lane]) + (ured[14][lane] + ured[15][lane])));
        usage_part[(size_t)blockIdx.x * 64 + lane] = s;
    }
}

__global__ __launch_bounds__(1024)
void router_aux(const float* __restrict__ usage_part, float* __restrict__ out) {
    __shared__ float red[16][NE];
    const int tid = threadIdx.x;    // 1024
    const int e   = tid & 63;
    const int g   = tid >> 6;       // 0..15
    float s = 0.f;
#pragma unroll
    for (int i = 0; i < NBLK / 16; ++i)
        s += usage_part[(size_t)(g * (NBLK / 16) + i) * 64 + e];
    red[g][e] = s;
    __syncthreads();
    if (g == 0) {
        float tot = 0.f;
#pragma unroll
        for (int i = 0; i < 16; ++i) tot += red[i][e];
        float u = tot * (1.0f / 16384.0f) - (1.0f / 64.0f);
        float sq = u * u;
#pragma unroll
        for (int off = 32; off >= 1; off >>= 1) sq += __shfl_xor(sq, off, 64);
        if (e == 0) out[65536] = sq;
    }
}

extern "C" void kernel_launch(void* const* d_in, const int* in_sizes, int n_in,
                              void* d_out, int out_size, void* d_ws, size_t ws_size,
                              hipStream_t stream) {
    const float* x = (const float*)d_in[0];   // [4,4096,2048] fp32
    const float* W = (const float*)d_in[1];   // [64,2048] fp32
    float* out     = (float*)d_out;           // 65537 floats

    // ws layout: Wh | Wm | Wl (packed bf16 planes, 256 KB each) | usage partials
    unsigned short* ws_h = (unsigned short*)d_ws;
    unsigned short* ws_m = ws_h + NPLANE;
    unsigned short* ws_l = ws_m + NPLANE;
    float* upart         = (float*)(ws_l + NPLANE);

    wsplit_kernel<<<dim3(NPLANE / 256), dim3(256), 0, stream>>>(W, ws_h, ws_m, ws_l);
    router_main<<<dim3(NBLK), dim3(1024), 0, stream>>>(x, ws_h, ws_m, ws_l, out, upart);
    router_aux<<<dim3(1), dim3(1024), 0, stream>>>(upart, out);
}

// Round 6
// 229.374 us; speedup vs baseline: 1.2253x; 1.2253x over previous
//
#include <hip/hip_runtime.h>
#include <math.h>

// Problem constants (fixed by reference setup_inputs)
#define T_TOK 16384
#define DDIM  2048
#define NE    64
#define NPLANE (NE * DDIM)      // 131072 elements per W split plane
#define NBLK  512               // token-group count (32 tokens each)
#define KSPLIT 8                // k-ranges of 256

typedef __attribute__((ext_vector_type(8))) short short8;   // 8 bf16 MFMA frag
typedef __attribute__((ext_vector_type(4))) float floatx4;  // MFMA C/D

union Frag8 { unsigned short u[8]; short8 v; };

__device__ __forceinline__ unsigned int bf16_rne_bits(float x) {
    unsigned int u = __builtin_bit_cast(unsigned int, x);
    return (u + 0x7fffu + ((u >> 16) & 1u)) & 0xffff0000u;
}

// async global->LDS DMA (fallback kernel only)
__device__ __forceinline__ void dma16(const float* g, float* lds) {
    __builtin_amdgcn_global_load_lds(
        (const __attribute__((address_space(1))) unsigned int*)g,
        (__attribute__((address_space(3))) unsigned int*)lds, 16, 0, 0);
}

// ---- pre-kernel: exact 3-way bf16 split of W, PACKED in MFMA-frag order ----
// packed idx = ((kc*4 + et)*4 + q)*128 + cl*8 + j
//   expert e = et*16 + cl,  k = kc*32 + q*8 + j
__global__ void wsplit_kernel(const float* __restrict__ W,
                              unsigned short* __restrict__ wh,
                              unsigned short* __restrict__ wm,
                              unsigned short* __restrict__ wl) {
    int i  = blockIdx.x * 256 + threadIdx.x;   // grid covers exactly NPLANE
    int j  = i & 7;
    int cl = (i >> 3) & 15;
    int q  = (i >> 7) & 3;
    int et = (i >> 9) & 3;
    int kc = i >> 11;                          // 0..63
    int e  = et * 16 + cl;
    int k  = kc * 32 + q * 8 + j;
    float w = W[e * DDIM + k];
    unsigned int hb = bf16_rne_bits(w);
    float r  = w - __builtin_bit_cast(float, hb);   // exact
    unsigned int mb = bf16_rne_bits(r);
    float r2 = r - __builtin_bit_cast(float, mb);   // exact
    unsigned int lb = bf16_rne_bits(r2);            // |err| <= 2^-24 |w|
    wh[i] = (unsigned short)(hb >> 16);
    wm[i] = (unsigned short)(mb >> 16);
    wl[i] = (unsigned short)(lb >> 16);
}

// ---- main (new): split-K, 1 wave per block, zero LDS, zero barriers ----
// Block b: kq = b&7 (k in [kq*256, kq*256+256)), tb = b>>3 (tokens tb*32..+32).
// Wave computes 32 tok x 64 exp x 256 k partial logits, writes fp32 partials.
// Every x element read exactly once chip-wide; B bitwise-identical to R4.
// 16 fully independent waves/CU; HW scheduler provides all latency hiding.
__global__ __launch_bounds__(64, 4)
void router_partial(const float* __restrict__ x,
                    const unsigned short* __restrict__ wh,
                    const unsigned short* __restrict__ wm,
                    const unsigned short* __restrict__ wl,
                    float* __restrict__ part) {
    const int lane = threadIdx.x;          // one wave
    const int b    = blockIdx.x;
    const int kq   = b & 7;
    const int tb   = b >> 3;
    const int cl   = lane & 15;            // frag row (token / expert)
    const int q    = lane >> 4;            // frag k-quad
    const int t0   = tb * 32;

    // A source: token t0 + mt*16 + cl, k = kq*256 + s*32 + q*8 + j
    const float* xa = x + (size_t)(t0 + cl) * DDIM + kq * 256 + q * 8;
    const unsigned lofs = (unsigned)((q * 16 + cl) << 3);

    floatx4 acc[2][4];
#pragma unroll
    for (int mt = 0; mt < 2; ++mt)
#pragma unroll
        for (int nt = 0; nt < 4; ++nt)
            acc[mt][nt] = (floatx4){0.f, 0.f, 0.f, 0.f};

    // raw A for step 0
    float4 a0[2], a1[2];
#pragma unroll
    for (int mt = 0; mt < 2; ++mt) {
        const float* ap = xa + (size_t)mt * 16 * DDIM;
        a0[mt] = *(const float4*)(ap);
        a1[mt] = *(const float4*)(ap + 4);
    }

#pragma unroll 1
    for (int s = 0; s < 8; ++s) {
        // split current A (consumes a0/a1 -> regs free for reload)
        short8 Ah[2], Am[2], Al[2];
#pragma unroll
        for (int mt = 0; mt < 2; ++mt) {
            float f[8] = {a0[mt].x, a0[mt].y, a0[mt].z, a0[mt].w,
                          a1[mt].x, a1[mt].y, a1[mt].z, a1[mt].w};
            Frag8 fh, fm, fl;
#pragma unroll
            for (int j = 0; j < 8; ++j) {
                unsigned int ub = __builtin_bit_cast(unsigned int, f[j]);
                unsigned int hb = ub & 0xffff0000u;
                float r = f[j] - __builtin_bit_cast(float, hb);   // exact
                unsigned int rb = __builtin_bit_cast(unsigned int, r);
                unsigned int mb = rb & 0xffff0000u;
                float r2 = r - __builtin_bit_cast(float, mb);     // exact
                unsigned int lb = __builtin_bit_cast(unsigned int, r2);
                fh.u[j] = (unsigned short)(hb >> 16);
                fm.u[j] = (unsigned short)(mb >> 16);
                fl.u[j] = (unsigned short)(lb >> 16);
            }
            Ah[mt] = fh.v; Am[mt] = fm.v; Al[mt] = fl.v;
        }

        // reload A for next step into the same regs (in flight across the
        // B-load + 48-MFMA tail below -> HBM latency hidden intra-wave)
        if (s + 1 < 8) {
#pragma unroll
            for (int mt = 0; mt < 2; ++mt) {
                const float* ap = xa + (size_t)mt * 16 * DDIM + (s + 1) * 32;
                a0[mt] = *(const float4*)(ap);
                a1[mt] = *(const float4*)(ap + 4);
            }
        }

        // B (packed, contiguous 1 KB per frag) + 6-pass MFMA
        const unsigned kc = (unsigned)(kq * 8 + s);
#pragma unroll
        for (int nt = 0; nt < 4; ++nt) {
            const unsigned o = (kc * 16u + (unsigned)nt * 4u) * 128u + lofs;
            short8 Bh = __builtin_bit_cast(short8, *(const uint4*)(wh + o));
            short8 Bm = __builtin_bit_cast(short8, *(const uint4*)(wm + o));
            short8 Bl = __builtin_bit_cast(short8, *(const uint4*)(wl + o));
#pragma unroll
            for (int mt = 0; mt < 2; ++mt) {
                floatx4 a = acc[mt][nt];
                a = __builtin_amdgcn_mfma_f32_16x16x32_bf16(Ah[mt], Bh, a, 0, 0, 0);
                a = __builtin_amdgcn_mfma_f32_16x16x32_bf16(Ah[mt], Bm, a, 0, 0, 0);
                a = __builtin_amdgcn_mfma_f32_16x16x32_bf16(Am[mt], Bh, a, 0, 0, 0);
                a = __builtin_amdgcn_mfma_f32_16x16x32_bf16(Am[mt], Bm, a, 0, 0, 0);
                a = __builtin_amdgcn_mfma_f32_16x16x32_bf16(Ah[mt], Bl, a, 0, 0, 0);
                a = __builtin_amdgcn_mfma_f32_16x16x32_bf16(Al[mt], Bh, a, 0, 0, 0);
                acc[mt][nt] = a;
            }
        }
    }

    // partials: part[kq][token][expert]. D: n(exp)=lane&15, m(tok)=q*4+reg
    float* pb = part + ((size_t)kq * T_TOK + (size_t)t0) * NE;
#pragma unroll
    for (int mt = 0; mt < 2; ++mt)
#pragma unroll
        for (int nt = 0; nt < 4; ++nt)
#pragma unroll
            for (int r = 0; r < 4; ++r)
                pb[(mt * 16 + q * 4 + r) * NE + nt * 16 + cl] = acc[mt][nt][r];
}

// ---- reduce: verified epilogue over the 8 k-partials ----
__global__ __launch_bounds__(256)
void router_reduce(const float* __restrict__ part, float* __restrict__ out,
                   float* __restrict__ usage_part) {
    __shared__ float ured[4][NE];
    const int tid  = threadIdx.x;
    const int lane = tid & 63;
    const int wv   = tid >> 6;            // 0..3
    const int t0   = blockIdx.x * 32;
    const size_t ps = (size_t)T_TOK * NE;

    float usage_acc = 0.f;
#pragma unroll 1
    for (int j = 0; j < 8; ++j) {
        const int t = t0 + wv * 8 + j;
        const float* pp = part + (size_t)t * NE + lane;
        float l = (((pp[0 * ps] + pp[1 * ps]) + (pp[2 * ps] + pp[3 * ps])) +
                   ((pp[4 * ps] + pp[5 * ps]) + (pp[6 * ps] + pp[7 * ps])));

        float v1 = l; int i1 = lane;
#pragma unroll
        for (int off = 32; off >= 1; off >>= 1) {
            float ov = __shfl_xor(v1, off, 64);
            int   oi = __shfl_xor(i1, off, 64);
            if (ov > v1 || (ov == v1 && oi < i1)) { v1 = ov; i1 = oi; }
        }
        float lm = (lane == i1) ? -INFINITY : l;
        float v2 = lm; int i2 = lane;
#pragma unroll
        for (int off = 32; off >= 1; off >>= 1) {
            float ov = __shfl_xor(v2, off, 64);
            int   oi = __shfl_xor(i2, off, 64);
            if (ov > v2 || (ov == v2 && oi < i2)) { v2 = ov; i2 = oi; }
        }

        float p = expf(l - v1);
        float s = p;
#pragma unroll
        for (int off = 32; off >= 1; off >>= 1) s += __shfl_xor(s, off, 64);

        float e2  = expf(v2 - v1);
        float rcp = 1.0f / (1.0f + e2);
        usage_acc += p / s;

        if (lane == 0) {
            out[(size_t)t * 2 + 0]         = (float)i1;
            out[(size_t)t * 2 + 1]         = (float)i2;
            out[32768 + (size_t)t * 2 + 0] = rcp;
            out[32768 + (size_t)t * 2 + 1] = e2 * rcp;
        }
    }

    ured[wv][lane] = usage_acc;
    __syncthreads();
    if (wv == 0) {
        float s = (ured[0][lane] + ured[1][lane]) + (ured[2][lane] + ured[3][lane]);
        usage_part[(size_t)blockIdx.x * 64 + lane] = s;
    }
}

// ---- fallback main (R4, verified 93 us, absmax 0.0) used if ws too small ----
__global__ __launch_bounds__(1024, 8)
void router_main_fb(const float* __restrict__ x,
                    const unsigned short* __restrict__ wh,
                    const unsigned short* __restrict__ wm,
                    const unsigned short* __restrict__ wl,
                    float* __restrict__ out, float* __restrict__ usage_part) {
    __shared__ float As[2 * 8192];
    __shared__ float ured[16][NE];
    float* lg = As;

    const int tid  = threadIdx.x;
    const int lane = tid & 63;
    const int wv   = __builtin_amdgcn_readfirstlane(tid >> 6);
    const int nh   = wv & 1;
    const int kq   = wv >> 1;
    const int cl   = lane & 15;
    const int q    = lane >> 4;
    const int t0   = blockIdx.x * 32;

    const int tlA0 = 2 * wv, tlA1 = 2 * wv + 1;
    const float* ax0 = x + (size_t)(t0 + tlA0) * DDIM + ((lane ^ (tlA0 & 7)) << 2);
    const float* ax1 = x + (size_t)(t0 + tlA1) * DDIM + ((lane ^ (tlA1 & 7)) << 2);

    floatx4 acc[2][2];
#pragma unroll
    for (int mt = 0; mt < 2; ++mt)
#pragma unroll
        for (int nt = 0; nt < 2; ++nt)
            acc[mt][nt] = (floatx4){0.f, 0.f, 0.f, 0.f};

    const unsigned lofs   = (unsigned)((q * 16 + cl) << 3);
    const unsigned bfrag0 = ((unsigned)(kq * 4 + nh * 2 + 0) << 9) + lofs;
    const unsigned bfrag1 = ((unsigned)(kq * 4 + nh * 2 + 1) << 9) + lofs;

    dma16(ax0, As + tlA0 * 256);
    dma16(ax1, As + tlA1 * 256);

#pragma unroll 1
    for (int c = 0; c < 8; ++c) {
        __syncthreads();
        if (c + 1 < 8) {
            float* nb = As + ((c + 1) & 1) * 8192;
            dma16(ax0 + (c + 1) * 256, nb + tlA0 * 256);
            dma16(ax1 + (c + 1) * 256, nb + tlA1 * 256);
        }
        const unsigned bo = (unsigned)c * 16384u;
        uint4 cb[2][3];
        {
            const unsigned o0 = bo + bfrag0, o1 = bo + bfrag1;
            cb[0][0] = *(const uint4*)(wh + o0);
            cb[0][1] = *(const uint4*)(wm + o0);
            cb[0][2] = *(const uint4*)(wl + o0);
            cb[1][0] = *(const uint4*)(wh + o1);
            cb[1][1] = *(const uint4*)(wm + o1);
            cb[1][2] = *(const uint4*)(wl + o1);
        }
        const float* buf = As + (c & 1) * 8192;
        const int h0 = (kq * 8 + q * 2) ^ (cl & 7);
        short8 Ah[2], Am[2], Al[2];
#pragma unroll
        for (int mt = 0; mt < 2; ++mt) {
            const float* ap = buf + (mt * 16 + cl) * 256;
            float4 a0 = *(const float4*)(ap + h0 * 4);
            float4 a1 = *(const float4*)(ap + (h0 ^ 1) * 4);
            float f[8] = {a0.x, a0.y, a0.z, a0.w, a1.x, a1.y, a1.z, a1.w};
            Frag8 fh, fm, fl;
#pragma unroll
            for (int j = 0; j < 8; ++j) {
                unsigned int ub = __builtin_bit_cast(unsigned int, f[j]);
                unsigned int hb = ub & 0xffff0000u;
                float r = f[j] - __builtin_bit_cast(float, hb);
                unsigned int rb = __builtin_bit_cast(unsigned int, r);
                unsigned int mb = rb & 0xffff0000u;
                float r2 = r - __builtin_bit_cast(float, mb);
                unsigned int lb = __builtin_bit_cast(unsigned int, r2);
                fh.u[j] = (unsigned short)(hb >> 16);
                fm.u[j] = (unsigned short)(mb >> 16);
                fl.u[j] = (unsigned short)(lb >> 16);
            }
            Ah[mt] = fh.v; Am[mt] = fm.v; Al[mt] = fl.v;
        }
#pragma unroll
        for (int mt = 0; mt < 2; ++mt)
#pragma unroll
            for (int nt = 0; nt < 2; ++nt) {
                short8 Bh = __builtin_bit_cast(short8, cb[nt][0]);
                short8 Bm = __builtin_bit_cast(short8, cb[nt][1]);
                short8 Bl = __builtin_bit_cast(short8, cb[nt][2]);
                floatx4 a = acc[mt][nt];
                a = __builtin_amdgcn_mfma_f32_16x16x32_bf16(Ah[mt], Bh, a, 0, 0, 0);
                a = __builtin_amdgcn_mfma_f32_16x16x32_bf16(Ah[mt], Bm, a, 0, 0, 0);
                a = __builtin_amdgcn_mfma_f32_16x16x32_bf16(Am[mt], Bh, a, 0, 0, 0);
                a = __builtin_amdgcn_mfma_f32_16x16x32_bf16(Am[mt], Bm, a, 0, 0, 0);
                a = __builtin_amdgcn_mfma_f32_16x16x32_bf16(Ah[mt], Bl, a, 0, 0, 0);
                a = __builtin_amdgcn_mfma_f32_16x16x32_bf16(Al[mt], Bh, a, 0, 0, 0);
                acc[mt][nt] = a;
            }
    }

    __syncthreads();
#pragma unroll
    for (int mt = 0; mt < 2; ++mt)
#pragma unroll
        for (int nt = 0; nt < 2; ++nt)
#pragma unroll
            for (int r = 0; r < 4; ++r)
                lg[kq * 2048 + (mt * 16 + q * 4 + r) * 64 + nh * 32 + nt * 16 + cl]
                    = acc[mt][nt][r];
    __syncthreads();

    float usage_acc = 0.f;
#pragma unroll 1
    for (int j = 0; j < 2; ++j) {
        const int tl = wv * 2 + j;
        const int t  = t0 + tl;
        float l = (((lg[0 * 2048 + tl * 64 + lane] + lg[1 * 2048 + tl * 64 + lane]) +
                    (lg[2 * 2048 + tl * 64 + lane] + lg[3 * 2048 + tl * 64 + lane])) +
                   ((lg[4 * 2048 + tl * 64 + lane] + lg[5 * 2048 + tl * 64 + lane]) +
                    (lg[6 * 2048 + tl * 64 + lane] + lg[7 * 2048 + tl * 64 + lane])));

        float v1 = l; int i1 = lane;
#pragma unroll
        for (int off = 32; off >= 1; off >>= 1) {
            float ov = __shfl_xor(v1, off, 64);
            int   oi = __shfl_xor(i1, off, 64);
            if (ov > v1 || (ov == v1 && oi < i1)) { v1 = ov; i1 = oi; }
        }
        float lm = (lane == i1) ? -INFINITY : l;
        float v2 = lm; int i2 = lane;
#pragma unroll
        for (int off = 32; off >= 1; off >>= 1) {
            float ov = __shfl_xor(v2, off, 64);
            int   oi = __shfl_xor(i2, off, 64);
            if (ov > v2 || (ov == v2 && oi < i2)) { v2 = ov; i2 = oi; }
        }

        float p = expf(l - v1);
        float s = p;
#pragma unroll
        for (int off = 32; off >= 1; off >>= 1) s += __shfl_xor(s, off, 64);

        float e2  = expf(v2 - v1);
        float rcp = 1.0f / (1.0f + e2);
        usage_acc += p / s;

        if (lane == 0) {
            out[(size_t)t * 2 + 0]         = (float)i1;
            out[(size_t)t * 2 + 1]         = (float)i2;
            out[32768 + (size_t)t * 2 + 0] = rcp;
            out[32768 + (size_t)t * 2 + 1] = e2 * rcp;
        }
    }

    ured[wv][lane] = usage_acc;
    __syncthreads();
    if (wv == 0) {
        float s = (((ured[0][lane] + ured[1][lane]) + (ured[2][lane] + ured[3][lane])) +
                   ((ured[4][lane] + ured[5][lane]) + (ured[6][lane] + ured[7][lane]))) +
                  (((ured[8][lane] + ured[9][lane]) + (ured[10][lane] + ured[11][lane])) +
                   ((ured[12][lane] + ured[13][lane]) + (ured[14][lane] + ured[15][lane])));
        usage_part[(size_t)blockIdx.x * 64 + lane] = s;
    }
}

__global__ __launch_bounds__(1024)
void router_aux(const float* __restrict__ usage_part, float* __restrict__ out) {
    __shared__ float red[16][NE];
    const int tid = threadIdx.x;    // 1024
    const int e   = tid & 63;
    const int g   = tid >> 6;       // 0..15
    float s = 0.f;
#pragma unroll
    for (int i = 0; i < NBLK / 16; ++i)
        s += usage_part[(size_t)(g * (NBLK / 16) + i) * 64 + e];
    red[g][e] = s;
    __syncthreads();
    if (g == 0) {
        float tot = 0.f;
#pragma unroll
        for (int i = 0; i < 16; ++i) tot += red[i][e];
        float u = tot * (1.0f / 16384.0f) - (1.0f / 64.0f);
        float sq = u * u;
#pragma unroll
        for (int off = 32; off >= 1; off >>= 1) sq += __shfl_xor(sq, off, 64);
        if (e == 0) out[65536] = sq;
    }
}

extern "C" void kernel_launch(void* const* d_in, const int* in_sizes, int n_in,
                              void* d_out, int out_size, void* d_ws, size_t ws_size,
                              hipStream_t stream) {
    const float* x = (const float*)d_in[0];   // [4,4096,2048] fp32
    const float* W = (const float*)d_in[1];   // [64,2048] fp32
    float* out     = (float*)d_out;           // 65537 floats

    unsigned short* ws_h = (unsigned short*)d_ws;
    unsigned short* ws_m = ws_h + NPLANE;
    unsigned short* ws_l = ws_m + NPLANE;
    char* ws_tail        = (char*)(ws_l + NPLANE);

    const size_t part_bytes = (size_t)KSPLIT * T_TOK * NE * sizeof(float); // 33.5 MB
    const size_t need = 3 * (size_t)NPLANE * sizeof(unsigned short)
                      + part_bytes + (size_t)NBLK * NE * sizeof(float);

    wsplit_kernel<<<dim3(NPLANE / 256), dim3(256), 0, stream>>>(W, ws_h, ws_m, ws_l);

    if (ws_size >= need) {
        float* part  = (float*)ws_tail;
        float* upart = part + (size_t)KSPLIT * T_TOK * NE;
        router_partial<<<dim3(NBLK * KSPLIT), dim3(64), 0, stream>>>(
            x, ws_h, ws_m, ws_l, part);
        router_reduce<<<dim3(NBLK), dim3(256), 0, stream>>>(part, out, upart);
        router_aux<<<dim3(1), dim3(1024), 0, stream>>>(upart, out);
    } else {
        float* upart = (float*)ws_tail;
        router_main_fb<<<dim3(NBLK), dim3(1024), 0, stream>>>(
            x, ws_h, ws_m, ws_l, out, upart);
        router_aux<<<dim3(1), dim3(1024), 0, stream>>>(upart, out);
    }
}

// Round 7
// 221.743 us; speedup vs baseline: 1.2674x; 1.0344x over previous
//
#include <hip/hip_runtime.h>
#include <math.h>

// Problem constants (fixed by reference setup_inputs)
#define T_TOK 16384
#define DDIM  2048
#define NE    64
#define NPLANE (NE * DDIM)      // 131072 elements per W split plane
#define NBLK  512               // main-kernel grid (32 tokens each)

typedef __attribute__((ext_vector_type(8))) short short8;   // 8 bf16 MFMA frag
typedef __attribute__((ext_vector_type(4))) float floatx4;  // MFMA C/D

union Frag8 { unsigned short u[8]; short8 v; };

__device__ __forceinline__ unsigned int bf16_rne_bits(float x) {
    unsigned int u = __builtin_bit_cast(unsigned int, x);
    return (u + 0x7fffu + ((u >> 16) & 1u)) & 0xffff0000u;
}

// async global->LDS DMA, 16 B per lane; LDS dest = uniform base + lane*16
__device__ __forceinline__ void dma16(const float* g, float* lds) {
    __builtin_amdgcn_global_load_lds(
        (const __attribute__((address_space(1))) unsigned int*)g,
        (__attribute__((address_space(3))) unsigned int*)lds, 16, 0, 0);
}

// ---- pre-kernel: exact 3-way bf16 split of W, PACKED in MFMA-frag order ----
// packed idx = ((kc*4 + et)*4 + q)*128 + cl*8 + j
//   expert e = et*16 + cl,  k = kc*32 + q*8 + j
// => a wave's B-frag load (fixed p, kc, et; lanes (q,cl)) is 1 KB contiguous.
__global__ void wsplit_kernel(const float* __restrict__ W,
                              unsigned short* __restrict__ wh,
                              unsigned short* __restrict__ wm,
                              unsigned short* __restrict__ wl) {
    int i  = blockIdx.x * 256 + threadIdx.x;   // grid covers exactly NPLANE
    int j  = i & 7;
    int cl = (i >> 3) & 15;
    int q  = (i >> 7) & 3;
    int et = (i >> 9) & 3;
    int kc = i >> 11;                          // 0..63
    int e  = et * 16 + cl;
    int k  = kc * 32 + q * 8 + j;
    float w = W[e * DDIM + k];
    unsigned int hb = bf16_rne_bits(w);
    float r  = w - __builtin_bit_cast(float, hb);   // exact
    unsigned int mb = bf16_rne_bits(r);
    float r2 = r - __builtin_bit_cast(float, mb);   // exact
    unsigned int lb = bf16_rne_bits(r2);            // |err| <= 2^-24 |w|
    wh[i] = (unsigned short)(hb >> 16);
    wm[i] = (unsigned short)(mb >> 16);
    wl[i] = (unsigned short)(lb >> 16);
}

// ---- main: R4 bit-for-bit, with the VGPR cap lifted.
// R4 ran __launch_bounds__(1024, 8) => <=64 VGPR; compiler chose 32 and
// spilled the ~90-reg step body to scratch (WRITE_SIZE 76 MB/dispatch, and
// scratch ops share vmcnt with staging loads -> every wait drains spills).
// (1024, 4) => 128 VGPR cap: live set fits, zero spills. Occupancy becomes
// 1 block/CU (16 waves) -- R3 showed 16 vs 30+ waves/CU is perf-neutral.
// Everything else (arithmetic, layouts, summation order) identical to R4
// (verified absmax 0.0).
__global__ __launch_bounds__(1024, 4)
void router_main(const float* __restrict__ x,
                 const unsigned short* __restrict__ wh,
                 const unsigned short* __restrict__ wm,
                 const unsigned short* __restrict__ wl,
                 float* __restrict__ out, float* __restrict__ usage_part) {
    __shared__ float As[2 * 8192];     // 64 KB staging; lg overlays after loop
    __shared__ float ured[16][NE];     // 4 KB
    float* lg = As;                    // [8][32][64] overlay (written post-loop)

    const int tid  = threadIdx.x;
    const int lane = tid & 63;
    const int wv   = __builtin_amdgcn_readfirstlane(tid >> 6);  // 0..15
    const int nh   = wv & 1;     // expert half (32 experts)
    const int kq   = wv >> 1;    // k sub-slice within each 256-k window
    const int cl   = lane & 15;  // frag row index (token / expert)
    const int q    = lane >> 4;  // frag k-quad
    const int t0   = blockIdx.x * 32;

    // A-DMA role: wave stages local tokens 2wv, 2wv+1. Lane l fetches 16-B
    // chunk (l ^ (tl&7)) of the 256-float window -> LDS linear [tl][l*16B].
    const int tlA0 = 2 * wv, tlA1 = 2 * wv + 1;
    const float* ax0 = x + (size_t)(t0 + tlA0) * DDIM + ((lane ^ (tlA0 & 7)) << 2);
    const float* ax1 = x + (size_t)(t0 + tlA1) * DDIM + ((lane ^ (tlA1 & 7)) << 2);

    floatx4 acc[2][2];
#pragma unroll
    for (int mt = 0; mt < 2; ++mt)
#pragma unroll
        for (int nt = 0; nt < 2; ++nt)
            acc[mt][nt] = (floatx4){0.f, 0.f, 0.f, 0.f};

    // B frag element offsets (phase c adds c*16384):
    //   ((c*8 + kq)*4 + (nh*2+nt))*512 + (q*16+cl)*8
    const unsigned lofs   = (unsigned)((q * 16 + cl) << 3);
    const unsigned bfrag0 = ((unsigned)(kq * 4 + nh * 2 + 0) << 9) + lofs;
    const unsigned bfrag1 = ((unsigned)(kq * 4 + nh * 2 + 1) << 9) + lofs;

    // prologue: DMA phase 0 -> buffer 0
    dma16(ax0, As + tlA0 * 256);
    dma16(ax1, As + tlA1 * 256);

#pragma unroll 1
    for (int c = 0; c < 8; ++c) {
        __syncthreads();   // drains DMA(c); also frees buf[(c+1)&1] for prefetch

        if (c + 1 < 8) {   // prefetch next 256-k window into alternate buffer
            float* nb = As + ((c + 1) & 1) * 8192;
            dma16(ax0 + (c + 1) * 256, nb + tlA0 * 256);
            dma16(ax1 + (c + 1) * 256, nb + tlA1 * 256);
        }

        // B frags: two 1-KB contiguous loads x 3 planes
        const unsigned bo = (unsigned)c * 16384u;
        uint4 cb[2][3];
        {
            const unsigned o0 = bo + bfrag0, o1 = bo + bfrag1;
            cb[0][0] = *(const uint4*)(wh + o0);
            cb[0][1] = *(const uint4*)(wm + o0);
            cb[0][2] = *(const uint4*)(wl + o0);
            cb[1][0] = *(const uint4*)(wh + o1);
            cb[1][1] = *(const uint4*)(wm + o1);
            cb[1][2] = *(const uint4*)(wl + o1);
        }

        // A frags from LDS (chunk-XOR by cl&7) + truncation 3-way split
        const float* buf = As + (c & 1) * 8192;
        const int h0 = (kq * 8 + q * 2) ^ (cl & 7);   // swizzled 16-B chunk idx
        short8 Ah[2], Am[2], Al[2];
#pragma unroll
        for (int mt = 0; mt < 2; ++mt) {
            const float* ap = buf + (mt * 16 + cl) * 256;
            float4 a0 = *(const float4*)(ap + h0 * 4);         // k j=0..3
            float4 a1 = *(const float4*)(ap + (h0 ^ 1) * 4);   // k j=4..7
            float f[8] = {a0.x, a0.y, a0.z, a0.w, a1.x, a1.y, a1.z, a1.w};
            Frag8 fh, fm, fl;
#pragma unroll
            for (int j = 0; j < 8; ++j) {
                unsigned int ub = __builtin_bit_cast(unsigned int, f[j]);
                unsigned int hb = ub & 0xffff0000u;
                float r = f[j] - __builtin_bit_cast(float, hb);   // exact
                unsigned int rb = __builtin_bit_cast(unsigned int, r);
                unsigned int mb = rb & 0xffff0000u;
                float r2 = r - __builtin_bit_cast(float, mb);     // exact
                unsigned int lb = __builtin_bit_cast(unsigned int, r2);
                fh.u[j] = (unsigned short)(hb >> 16);
                fm.u[j] = (unsigned short)(mb >> 16);
                fl.u[j] = (unsigned short)(lb >> 16);
            }
            Ah[mt] = fh.v; Am[mt] = fm.v; Al[mt] = fl.v;
        }

        // 6 passes: hh + hm + mh + mm + hl + lh
#pragma unroll
        for (int mt = 0; mt < 2; ++mt)
#pragma unroll
            for (int nt = 0; nt < 2; ++nt) {
                short8 Bh = __builtin_bit_cast(short8, cb[nt][0]);
                short8 Bm = __builtin_bit_cast(short8, cb[nt][1]);
                short8 Bl = __builtin_bit_cast(short8, cb[nt][2]);
                floatx4 a = acc[mt][nt];
                a = __builtin_amdgcn_mfma_f32_16x16x32_bf16(Ah[mt], Bh, a, 0, 0, 0);
                a = __builtin_amdgcn_mfma_f32_16x16x32_bf16(Ah[mt], Bm, a, 0, 0, 0);
                a = __builtin_amdgcn_mfma_f32_16x16x32_bf16(Am[mt], Bh, a, 0, 0, 0);
                a = __builtin_amdgcn_mfma_f32_16x16x32_bf16(Am[mt], Bm, a, 0, 0, 0);
                a = __builtin_amdgcn_mfma_f32_16x16x32_bf16(Ah[mt], Bl, a, 0, 0, 0);
                a = __builtin_amdgcn_mfma_f32_16x16x32_bf16(Al[mt], Bh, a, 0, 0, 0);
                acc[mt][nt] = a;
            }
    }

    __syncthreads();   // all waves done reading As -> safe to overlay lg

    // partial logits -> lg. D layout: n(expert) = lane&15, m(token) = q*4+reg
#pragma unroll
    for (int mt = 0; mt < 2; ++mt)
#pragma unroll
        for (int nt = 0; nt < 2; ++nt)
#pragma unroll
            for (int r = 0; r < 4; ++r)
                lg[kq * 2048 + (mt * 16 + q * 4 + r) * 64 + nh * 32 + nt * 16 + cl]
                    = acc[mt][nt][r];
    __syncthreads();

    // ---- epilogue (verified rounds 0-6): lane = expert, 2 tokens/wave ----
    float usage_acc = 0.f;
#pragma unroll 1
    for (int j = 0; j < 2; ++j) {
        const int tl = wv * 2 + j;
        const int t  = t0 + tl;
        float l = (((lg[0 * 2048 + tl * 64 + lane] + lg[1 * 2048 + tl * 64 + lane]) +
                    (lg[2 * 2048 + tl * 64 + lane] + lg[3 * 2048 + tl * 64 + lane])) +
                   ((lg[4 * 2048 + tl * 64 + lane] + lg[5 * 2048 + tl * 64 + lane]) +
                    (lg[6 * 2048 + tl * 64 + lane] + lg[7 * 2048 + tl * 64 + lane])));

        float v1 = l; int i1 = lane;
#pragma unroll
        for (int off = 32; off >= 1; off >>= 1) {
            float ov = __shfl_xor(v1, off, 64);
            int   oi = __shfl_xor(i1, off, 64);
            if (ov > v1 || (ov == v1 && oi < i1)) { v1 = ov; i1 = oi; }
        }
        float lm = (lane == i1) ? -INFINITY : l;
        float v2 = lm; int i2 = lane;
#pragma unroll
        for (int off = 32; off >= 1; off >>= 1) {
            float ov = __shfl_xor(v2, off, 64);
            int   oi = __shfl_xor(i2, off, 64);
            if (ov > v2 || (ov == v2 && oi < i2)) { v2 = ov; i2 = oi; }
        }

        float p = expf(l - v1);
        float s = p;
#pragma unroll
        for (int off = 32; off >= 1; off >>= 1) s += __shfl_xor(s, off, 64);

        float e2  = expf(v2 - v1);
        float rcp = 1.0f / (1.0f + e2);
        usage_acc += p / s;

        if (lane == 0) {
            out[(size_t)t * 2 + 0]         = (float)i1;
            out[(size_t)t * 2 + 1]         = (float)i2;
            out[32768 + (size_t)t * 2 + 0] = rcp;
            out[32768 + (size_t)t * 2 + 1] = e2 * rcp;
        }
    }

    // per-block usage partials (no atomics; deterministic)
    ured[wv][lane] = usage_acc;
    __syncthreads();
    if (wv == 0) {
        float s = (((ured[0][lane] + ured[1][lane]) + (ured[2][lane] + ured[3][lane])) +
                   ((ured[4][lane] + ured[5][lane]) + (ured[6][lane] + ured[7][lane]))) +
                  (((ured[8][lane] + ured[9][lane]) + (ured[10][lane] + ured[11][lane])) +
                   ((ured[12][lane] + ured[13][lane]) + (ured[14][lane] + ured[15][lane])));
        usage_part[(size_t)blockIdx.x * 64 + lane] = s;
    }
}

__global__ __launch_bounds__(1024)
void router_aux(const float* __restrict__ usage_part, float* __restrict__ out) {
    __shared__ float red[16][NE];
    const int tid = threadIdx.x;    // 1024
    const int e   = tid & 63;
    const int g   = tid >> 6;       // 0..15
    float s = 0.f;
#pragma unroll
    for (int i = 0; i < NBLK / 16; ++i)
        s += usage_part[(size_t)(g * (NBLK / 16) + i) * 64 + e];
    red[g][e] = s;
    __syncthreads();
    if (g == 0) {
        float tot = 0.f;
#pragma unroll
        for (int i = 0; i < 16; ++i) tot += red[i][e];
        float u = tot * (1.0f / 16384.0f) - (1.0f / 64.0f);
        float sq = u * u;
#pragma unroll
        for (int off = 32; off >= 1; off >>= 1) sq += __shfl_xor(sq, off, 64);
        if (e == 0) out[65536] = sq;
    }
}

extern "C" void kernel_launch(void* const* d_in, const int* in_sizes, int n_in,
                              void* d_out, int out_size, void* d_ws, size_t ws_size,
                              hipStream_t stream) {
    const float* x = (const float*)d_in[0];   // [4,4096,2048] fp32
    const float* W = (const float*)d_in[1];   // [64,2048] fp32
    float* out     = (float*)d_out;           // 65537 floats

    // ws layout: Wh | Wm | Wl (packed bf16 planes, 256 KB each) | usage partials
    unsigned short* ws_h = (unsigned short*)d_ws;
    unsigned short* ws_m = ws_h + NPLANE;
    unsigned short* ws_l = ws_m + NPLANE;
    float* upart         = (float*)(ws_l + NPLANE);

    wsplit_kernel<<<dim3(NPLANE / 256), dim3(256), 0, stream>>>(W, ws_h, ws_m, ws_l);
    router_main<<<dim3(NBLK), dim3(1024), 0, stream>>>(x, ws_h, ws_m, ws_l, out, upart);
    router_aux<<<dim3(1), dim3(1024), 0, stream>>>(upart, out);
}

// Round 8
// 215.121 us; speedup vs baseline: 1.3065x; 1.0308x over previous
//
#include <hip/hip_runtime.h>
#include <math.h>

// Problem constants (fixed by reference setup_inputs)
#define T_TOK 16384
#define DDIM  2048
#define NE    64
#define NPLANE (NE * DDIM)      // 131072 elements per W split plane
#define NBLK  512               // main-kernel grid (32 tokens each)

typedef __attribute__((ext_vector_type(8))) short short8;   // 8 bf16 MFMA frag
typedef __attribute__((ext_vector_type(4))) float floatx4;  // MFMA C/D

union Frag8 { unsigned short u[8]; short8 v; };

__device__ __forceinline__ unsigned int bf16_rne_bits(float x) {
    unsigned int u = __builtin_bit_cast(unsigned int, x);
    return (u + 0x7fffu + ((u >> 16) & 1u)) & 0xffff0000u;
}

// async global->LDS DMA, 16 B per lane; LDS dest = uniform base + lane*16
__device__ __forceinline__ void dma16(const float* g, float* lds) {
    __builtin_amdgcn_global_load_lds(
        (const __attribute__((address_space(1))) unsigned int*)g,
        (__attribute__((address_space(3))) unsigned int*)lds, 16, 0, 0);
}

// ---- pre-kernel: exact 3-way bf16 split of W, PACKED in MFMA-frag order ----
// packed idx = ((kc*4 + et)*4 + q)*128 + cl*8 + j
//   expert e = et*16 + cl,  k = kc*32 + q*8 + j
// => a wave's B-frag load (fixed p, kc, et; lanes (q,cl)) is 1 KB contiguous.
__global__ void wsplit_kernel(const float* __restrict__ W,
                              unsigned short* __restrict__ wh,
                              unsigned short* __restrict__ wm,
                              unsigned short* __restrict__ wl) {
    int i  = blockIdx.x * 256 + threadIdx.x;   // grid covers exactly NPLANE
    int j  = i & 7;
    int cl = (i >> 3) & 15;
    int q  = (i >> 7) & 3;
    int et = (i >> 9) & 3;
    int kc = i >> 11;                          // 0..63
    int e  = et * 16 + cl;
    int k  = kc * 32 + q * 8 + j;
    float w = W[e * DDIM + k];
    unsigned int hb = bf16_rne_bits(w);
    float r  = w - __builtin_bit_cast(float, hb);   // exact
    unsigned int mb = bf16_rne_bits(r);
    float r2 = r - __builtin_bit_cast(float, mb);   // exact
    unsigned int lb = bf16_rne_bits(r2);            // |err| <= 2^-24 |w|
    wh[i] = (unsigned short)(hb >> 16);
    wm[i] = (unsigned short)(mb >> 16);
    wl[i] = (unsigned short)(lb >> 16);
}

// ---- main: R7 with ONE change: DMA prefetch issued AFTER the B loads.
// vmcnt is a FIFO: R7 issued [dma x2][B x6], so the compiler's wait before
// the first cb use had to retire the DMAs too -> every phase serially paid
// DMA-round-trip + B-round-trip + compute (the ~23k-cycle phase). Issuing
// [B x6][dma x2] makes the cb-wait vmcnt(2): the prefetch DMAs stay in
// flight across the whole phase body and only drain at the phase-end
// barrier (the m97 pattern). sched_barrier(0) pins the issue order.
// Same loads, same values, same sums -> absmax 0.0 structurally.
__global__ __launch_bounds__(1024, 4)
void router_main(const float* __restrict__ x,
                 const unsigned short* __restrict__ wh,
                 const unsigned short* __restrict__ wm,
                 const unsigned short* __restrict__ wl,
                 float* __restrict__ out, float* __restrict__ usage_part) {
    __shared__ float As[2 * 8192];     // 64 KB staging; lg overlays after loop
    __shared__ float ured[16][NE];     // 4 KB
    float* lg = As;                    // [8][32][64] overlay (written post-loop)

    const int tid  = threadIdx.x;
    const int lane = tid & 63;
    const int wv   = __builtin_amdgcn_readfirstlane(tid >> 6);  // 0..15
    const int nh   = wv & 1;     // expert half (32 experts)
    const int kq   = wv >> 1;    // k sub-slice within each 256-k window
    const int cl   = lane & 15;  // frag row index (token / expert)
    const int q    = lane >> 4;  // frag k-quad
    const int t0   = blockIdx.x * 32;

    // A-DMA role: wave stages local tokens 2wv, 2wv+1. Lane l fetches 16-B
    // chunk (l ^ (tl&7)) of the 256-float window -> LDS linear [tl][l*16B].
    const int tlA0 = 2 * wv, tlA1 = 2 * wv + 1;
    const float* ax0 = x + (size_t)(t0 + tlA0) * DDIM + ((lane ^ (tlA0 & 7)) << 2);
    const float* ax1 = x + (size_t)(t0 + tlA1) * DDIM + ((lane ^ (tlA1 & 7)) << 2);

    floatx4 acc[2][2];
#pragma unroll
    for (int mt = 0; mt < 2; ++mt)
#pragma unroll
        for (int nt = 0; nt < 2; ++nt)
            acc[mt][nt] = (floatx4){0.f, 0.f, 0.f, 0.f};

    // B frag element offsets (phase c adds c*16384):
    //   ((c*8 + kq)*4 + (nh*2+nt))*512 + (q*16+cl)*8
    const unsigned lofs   = (unsigned)((q * 16 + cl) << 3);
    const unsigned bfrag0 = ((unsigned)(kq * 4 + nh * 2 + 0) << 9) + lofs;
    const unsigned bfrag1 = ((unsigned)(kq * 4 + nh * 2 + 1) << 9) + lofs;

    // prologue: DMA phase 0 -> buffer 0
    dma16(ax0, As + tlA0 * 256);
    dma16(ax1, As + tlA1 * 256);

#pragma unroll 1
    for (int c = 0; c < 8; ++c) {
        __syncthreads();   // drains DMA(c) (publish buffer c); frees alt buffer

        // B frags FIRST: two 1-KB contiguous loads x 3 planes (vmcnt FIFO
        // slots 7..2 after the DMAs below are issued)
        const unsigned bo = (unsigned)c * 16384u;
        uint4 cb[2][3];
        {
            const unsigned o0 = bo + bfrag0, o1 = bo + bfrag1;
            cb[0][0] = *(const uint4*)(wh + o0);
            cb[0][1] = *(const uint4*)(wm + o0);
            cb[0][2] = *(const uint4*)(wl + o0);
            cb[1][0] = *(const uint4*)(wh + o1);
            cb[1][1] = *(const uint4*)(wm + o1);
            cb[1][2] = *(const uint4*)(wl + o1);
        }
        __builtin_amdgcn_sched_barrier(0);   // pin: cb issued before DMAs

        if (c + 1 < 8) {   // prefetch next 256-k window into alternate buffer
            float* nb = As + ((c + 1) & 1) * 8192;
            dma16(ax0 + (c + 1) * 256, nb + tlA0 * 256);
            dma16(ax1 + (c + 1) * 256, nb + tlA1 * 256);
        }
        __builtin_amdgcn_sched_barrier(0);   // pin: DMAs issued here, early

        // A frags from LDS (chunk-XOR by cl&7) + truncation 3-way split
        const float* buf = As + (c & 1) * 8192;
        const int h0 = (kq * 8 + q * 2) ^ (cl & 7);   // swizzled 16-B chunk idx
        short8 Ah[2], Am[2], Al[2];
#pragma unroll
        for (int mt = 0; mt < 2; ++mt) {
            const float* ap = buf + (mt * 16 + cl) * 256;
            float4 a0 = *(const float4*)(ap + h0 * 4);         // k j=0..3
            float4 a1 = *(const float4*)(ap + (h0 ^ 1) * 4);   // k j=4..7
            float f[8] = {a0.x, a0.y, a0.z, a0.w, a1.x, a1.y, a1.z, a1.w};
            Frag8 fh, fm, fl;
#pragma unroll
            for (int j = 0; j < 8; ++j) {
                unsigned int ub = __builtin_bit_cast(unsigned int, f[j]);
                unsigned int hb = ub & 0xffff0000u;
                float r = f[j] - __builtin_bit_cast(float, hb);   // exact
                unsigned int rb = __builtin_bit_cast(unsigned int, r);
                unsigned int mb = rb & 0xffff0000u;
                float r2 = r - __builtin_bit_cast(float, mb);     // exact
                unsigned int lb = __builtin_bit_cast(unsigned int, r2);
                fh.u[j] = (unsigned short)(hb >> 16);
                fm.u[j] = (unsigned short)(mb >> 16);
                fl.u[j] = (unsigned short)(lb >> 16);
            }
            Ah[mt] = fh.v; Am[mt] = fm.v; Al[mt] = fl.v;
        }

        // 6 passes: hh + hm + mh + mm + hl + lh
#pragma unroll
        for (int mt = 0; mt < 2; ++mt)
#pragma unroll
            for (int nt = 0; nt < 2; ++nt) {
                short8 Bh = __builtin_bit_cast(short8, cb[nt][0]);
                short8 Bm = __builtin_bit_cast(short8, cb[nt][1]);
                short8 Bl = __builtin_bit_cast(short8, cb[nt][2]);
                floatx4 a = acc[mt][nt];
                a = __builtin_amdgcn_mfma_f32_16x16x32_bf16(Ah[mt], Bh, a, 0, 0, 0);
                a = __builtin_amdgcn_mfma_f32_16x16x32_bf16(Ah[mt], Bm, a, 0, 0, 0);
                a = __builtin_amdgcn_mfma_f32_16x16x32_bf16(Am[mt], Bh, a, 0, 0, 0);
                a = __builtin_amdgcn_mfma_f32_16x16x32_bf16(Am[mt], Bm, a, 0, 0, 0);
                a = __builtin_amdgcn_mfma_f32_16x16x32_bf16(Ah[mt], Bl, a, 0, 0, 0);
                a = __builtin_amdgcn_mfma_f32_16x16x32_bf16(Al[mt], Bh, a, 0, 0, 0);
                acc[mt][nt] = a;
            }
    }

    __syncthreads();   // all waves done reading As -> safe to overlay lg

    // partial logits -> lg. D layout: n(expert) = lane&15, m(token) = q*4+reg
#pragma unroll
    for (int mt = 0; mt < 2; ++mt)
#pragma unroll
        for (int nt = 0; nt < 2; ++nt)
#pragma unroll
            for (int r = 0; r < 4; ++r)
                lg[kq * 2048 + (mt * 16 + q * 4 + r) * 64 + nh * 32 + nt * 16 + cl]
                    = acc[mt][nt][r];
    __syncthreads();

    // ---- epilogue (verified rounds 0-7): lane = expert, 2 tokens/wave ----
    float usage_acc = 0.f;
#pragma unroll 1
    for (int j = 0; j < 2; ++j) {
        const int tl = wv * 2 + j;
        const int t  = t0 + tl;
        float l = (((lg[0 * 2048 + tl * 64 + lane] + lg[1 * 2048 + tl * 64 + lane]) +
                    (lg[2 * 2048 + tl * 64 + lane] + lg[3 * 2048 + tl * 64 + lane])) +
                   ((lg[4 * 2048 + tl * 64 + lane] + lg[5 * 2048 + tl * 64 + lane]) +
                    (lg[6 * 2048 + tl * 64 + lane] + lg[7 * 2048 + tl * 64 + lane])));

        float v1 = l; int i1 = lane;
#pragma unroll
        for (int off = 32; off >= 1; off >>= 1) {
            float ov = __shfl_xor(v1, off, 64);
            int   oi = __shfl_xor(i1, off, 64);
            if (ov > v1 || (ov == v1 && oi < i1)) { v1 = ov; i1 = oi; }
        }
        float lm = (lane == i1) ? -INFINITY : l;
        float v2 = lm; int i2 = lane;
#pragma unroll
        for (int off = 32; off >= 1; off >>= 1) {
            float ov = __shfl_xor(v2, off, 64);
            int   oi = __shfl_xor(i2, off, 64);
            if (ov > v2 || (ov == v2 && oi < i2)) { v2 = ov; i2 = oi; }
        }

        float p = expf(l - v1);
        float s = p;
#pragma unroll
        for (int off = 32; off >= 1; off >>= 1) s += __shfl_xor(s, off, 64);

        float e2  = expf(v2 - v1);
        float rcp = 1.0f / (1.0f + e2);
        usage_acc += p / s;

        if (lane == 0) {
            out[(size_t)t * 2 + 0]         = (float)i1;
            out[(size_t)t * 2 + 1]         = (float)i2;
            out[32768 + (size_t)t * 2 + 0] = rcp;
            out[32768 + (size_t)t * 2 + 1] = e2 * rcp;
        }
    }

    // per-block usage partials (no atomics; deterministic)
    ured[wv][lane] = usage_acc;
    __syncthreads();
    if (wv == 0) {
        float s = (((ured[0][lane] + ured[1][lane]) + (ured[2][lane] + ured[3][lane])) +
                   ((ured[4][lane] + ured[5][lane]) + (ured[6][lane] + ured[7][lane]))) +
                  (((ured[8][lane] + ured[9][lane]) + (ured[10][lane] + ured[11][lane])) +
                   ((ured[12][lane] + ured[13][lane]) + (ured[14][lane] + ured[15][lane])));
        usage_part[(size_t)blockIdx.x * 64 + lane] = s;
    }
}

__global__ __launch_bounds__(1024)
void router_aux(const float* __restrict__ usage_part, float* __restrict__ out) {
    __shared__ float red[16][NE];
    const int tid = threadIdx.x;    // 1024
    const int e   = tid & 63;
    const int g   = tid >> 6;       // 0..15
    float s = 0.f;
#pragma unroll
    for (int i = 0; i < NBLK / 16; ++i)
        s += usage_part[(size_t)(g * (NBLK / 16) + i) * 64 + e];
    red[g][e] = s;
    __syncthreads();
    if (g == 0) {
        float tot = 0.f;
#pragma unroll
        for (int i = 0; i < 16; ++i) tot += red[i][e];
        float u = tot * (1.0f / 16384.0f) - (1.0f / 64.0f);
        float sq = u * u;
#pragma unroll
        for (int off = 32; off >= 1; off >>= 1) sq += __shfl_xor(sq, off, 64);
        if (e == 0) out[65536] = sq;
    }
}

extern "C" void kernel_launch(void* const* d_in, const int* in_sizes, int n_in,
                              void* d_out, int out_size, void* d_ws, size_t ws_size,
                              hipStream_t stream) {
    const float* x = (const float*)d_in[0];   // [4,4096,2048] fp32
    const float* W = (const float*)d_in[1];   // [64,2048] fp32
    float* out     = (float*)d_out;           // 65537 floats

    // ws layout: Wh | Wm | Wl (packed bf16 planes, 256 KB each) | usage partials
    unsigned short* ws_h = (unsigned short*)d_ws;
    unsigned short* ws_m = ws_h + NPLANE;
    unsigned short* ws_l = ws_m + NPLANE;
    float* upart         = (float*)(ws_l + NPLANE);

    wsplit_kernel<<<dim3(NPLANE / 256), dim3(256), 0, stream>>>(W, ws_h, ws_m, ws_l);
    router_main<<<dim3(NBLK), dim3(1024), 0, stream>>>(x, ws_h, ws_m, ws_l, out, upart);
    router_aux<<<dim3(1), dim3(1024), 0, stream>>>(upart, out);
}